// Round 8
// baseline (311.532 us; speedup 1.0000x reference)
//
#include <hip/hip_runtime.h>
#include <hip/hip_fp16.h>

// CRF NLL on MI355X — round 8: f16 packed-math chain + fused combine.
//
// partition_b = log( a0 . (prod_t M_t) . exp(end) ),  M_t = ET . diag(ee_t).
// 32 chunks x 32 matrices per batch; each wave runs 4 interleaved chains
// (r7 structure: 4 waves/block, 2 blocks/batch, 4 blocks/CU). Step now in
// f16: S = pk_mul(pkrtz(D), s_packed) -> mfma_f32_32x32x16_f16 (PI-aligned:
// C/D reg order == next B operand order; zero cross-lane). Scale 2^-6.5 per
// matrix keeps state ~O(1) in f16 range (exact: added back as napp*6.5*ln2).
// Combine is fused: last-finishing block per batch (device-scope atomic +
// threadfence) runs the 32-step vector chain inline. One kernel total.
//
// ws (dwords): [0, FRAG) fragments (512 per (b,c));
//   FRAG+0..511 msum[b]; +512..1023 score[b]; +1024..1535 ready[b];
//   +1536.. napp[b*32+c].

typedef __attribute__((ext_vector_type(8)))  _Float16 half8;
typedef __attribute__((ext_vector_type(2)))  _Float16 half2v;
typedef __attribute__((ext_vector_type(16))) float    f32x16;
typedef __attribute__((ext_vector_type(4)))  unsigned uint4v;

#define S_N 1024
#define T_N 32
#define B_N 512
#define L_CH 32
#define C_CH 32
#define SCALE_MUL 0.011048543456039806f   // 2^-6.5 folded into ee
#define SCALE_LOG 4.505456673639645f      // 6.5*ln2 per applied matrix

#define WS_FRAG_DW ((size_t)B_N * C_CH * 512)          // 32 MiB
#define WS_MSUM_OFF (WS_FRAG_DW)
#define WS_SCORE_OFF (WS_FRAG_DW + 512)
#define WS_READY_OFF (WS_FRAG_DW + 1024)
#define WS_NAPP_OFF (WS_FRAG_DW + 1536)

__device__ __forceinline__ unsigned pkrtz(float lo, float hi) {
    return __builtin_bit_cast(unsigned, __builtin_amdgcn_cvt_pkrtz(lo, hi));
}
__device__ __forceinline__ unsigned pmul(unsigned a, unsigned b) {
    const __half2 r = __builtin_bit_cast(__half2, a) * __builtin_bit_cast(__half2, b);
    return __builtin_bit_cast(unsigned, r);
}
__device__ __forceinline__ half8 mkh8(const unsigned* a) {
    uint4v u = {a[0], a[1], a[2], a[3]};
    return __builtin_bit_cast(half8, u);
}
__device__ __forceinline__ float hlo(unsigned u) {
    return (float)__builtin_bit_cast(half2v, u).x;
}
__device__ __forceinline__ float hhi(unsigned u) {
    return (float)__builtin_bit_cast(half2v, u).y;
}
// PI: involution swapping rows 4-7<->8-11 and 20-23<->24-27
__device__ __forceinline__ int PIx(int x) { return (x & ~12) | ((x & 4) << 1) | ((x & 8) >> 1); }

__global__ __launch_bounds__(256, 4) void crf_chunk(
    const float* __restrict__ em, const int* __restrict__ tags,
    const float* __restrict__ mask, const float* __restrict__ trans,
    const float* __restrict__ startT, const float* __restrict__ endT,
    unsigned* __restrict__ wsf, float* __restrict__ wsflt,
    float* __restrict__ out)
{
    __shared__ unsigned elds[16][512];     // 32 KiB: 16 chunks x 2 KiB
    __shared__ int winner;
    const int wib  = threadIdx.x >> 6;
    const int lane = threadIdx.x & 63;
    const int n    = lane & 31;
    const int h    = lane >> 5;
    const int b    = blockIdx.x >> 1;
    const int half = blockIdx.x & 1;
    const int c0   = half * 16 + wib * 4;  // this wave's first chunk

    // ---- stage packed f16 scales for 4 chunks ----
    // dword (r, m=h*8+q) = half2(ee[r][base(m)], ee[r][base(m)+1]) in D-reg-pair order
    #pragma unroll
    for (int q = 0; q < 4; ++q) {
        const float* eq = em + ((size_t)b * S_N + (c0 + q) * L_CH) * T_N;
        unsigned* mq = elds[wib * 4 + q];
        #pragma unroll
        for (int i = 0; i < 8; ++i) {
            const int flat = i * 64 + lane;
            const int r = flat >> 4, m = flat & 15;
            const int base = ((m & 4) << 2) + ((m & 2) << 2) + ((m & 1) << 1) + ((m >> 3) << 2);
            const float2 v = *(const float2*)(eq + r * 32 + base);
            mq[r * 16 + m] = pkrtz(__expf(v.x) * SCALE_MUL, __expf(v.y) * SCALE_MUL);
        }
    }

    // ---- mask ballots (4 chunks) + fused path-score partial ----
    unsigned mb_[4];
    {
        float vacc = 0.f, macc = 0.f;
        #pragma unroll
        for (int q2 = 0; q2 < 2; ++q2) {
            const int s  = c0 * L_CH + q2 * 64 + lane;
            const float mv = mask[b * S_N + s];
            const unsigned long long mb = __ballot(mv != 0.0f);
            mb_[2 * q2]     = (unsigned)mb;
            mb_[2 * q2 + 1] = (unsigned)(mb >> 32);
            const int tc = tags[b * S_N + s];
            int tp = __shfl_up(tc, 1, 64);
            float val;
            if (lane == 0) {
                if (s == 0) {
                    val = startT[tc] + em[(size_t)b * S_N * T_N + tc];
                } else {
                    tp = tags[b * S_N + s - 1];
                    val = mv * (em[((size_t)b * S_N + s) * T_N + tc] + trans[tp * 32 + tc]);
                }
            } else {
                val = mv * (em[((size_t)b * S_N + s) * T_N + tc] + trans[tp * 32 + tc]);
            }
            vacc += val; macc += mv;
        }
        if (c0 == 0) mb_[0] &= ~1u;        // t=0 has no transition matrix
        #pragma unroll
        for (int d = 32; d > 0; d >>= 1) {
            vacc += __shfl_xor(vacc, d, 64);
            macc += __shfl_xor(macc, d, 64);
        }
        if (lane == 0) {
            atomicAdd(&wsflt[WS_SCORE_OFF + b], vacc);
            atomicAdd(&wsflt[WS_MSUM_OFF + b], macc);
            #pragma unroll
            for (int q = 0; q < 4; ++q)
                wsflt[WS_NAPP_OFF + b * C_CH + c0 + q] = (float)__popc(mb_[q]);
        }
    }

    // ---- loop-invariant A fragments: f16(exp(trans)), PI-permuted cols ----
    unsigned A1[4], A2[4];
    #pragma unroll
    for (int j = 0; j < 4; ++j) {
        const int k1 = PIx(8 * h + 2 * j);
        const int k2 = PIx(16 + 8 * h + 2 * j);
        A1[j] = pkrtz(__expf(trans[n * 32 + k1]), __expf(trans[n * 32 + k1 + 1]));
        A2[j] = pkrtz(__expf(trans[n * 32 + k2]), __expf(trans[n * 32 + k2 + 1]));
    }
    const half8 A1v = mkh8(A1), A2v = mkh8(A2);
    const f32x16 Zacc = {};

    // ---- 4 chain states: identity in C layout ----
    f32x16 D0, D1, D2, D3;
    #pragma unroll
    for (int i = 0; i < 16; ++i) {
        const int row = (i & 3) + 8 * (i >> 2) + 4 * h;
        const float v = (row == n) ? 1.0f : 0.0f;
        D0[i] = v; D1[i] = v; D2[i] = v; D3[i] = v;
    }

    const unsigned* m0 = elds[wib * 4];
    const unsigned* m1 = elds[wib * 4 + 1];
    const unsigned* m2 = elds[wib * 4 + 2];
    const unsigned* m3 = elds[wib * 4 + 3];

    #define STEP(D, mq, r_) { \
        const uint4 su = *(const uint4*)((mq) + (r_) * 16 + h * 8); \
        const uint4 sv = *(const uint4*)((mq) + (r_) * 16 + h * 8 + 4); \
        unsigned S[8]; \
        S[0] = pmul(pkrtz(D[0],  D[1]),  su.x); \
        S[1] = pmul(pkrtz(D[2],  D[3]),  su.y); \
        S[2] = pmul(pkrtz(D[4],  D[5]),  su.z); \
        S[3] = pmul(pkrtz(D[6],  D[7]),  su.w); \
        S[4] = pmul(pkrtz(D[8],  D[9]),  sv.x); \
        S[5] = pmul(pkrtz(D[10], D[11]), sv.y); \
        S[6] = pmul(pkrtz(D[12], D[13]), sv.z); \
        S[7] = pmul(pkrtz(D[14], D[15]), sv.w); \
        f32x16 t_ = __builtin_amdgcn_mfma_f32_32x32x16_f16(A1v, mkh8(&S[0]), Zacc, 0, 0, 0); \
        D = __builtin_amdgcn_mfma_f32_32x32x16_f16(A2v, mkh8(&S[4]), t_, 0, 0, 0); \
    }

    const bool allclean =
        ((mb_[0] | (c0 == 0 ? 1u : 0u)) == 0xFFFFFFFFu) &&
        (mb_[1] == 0xFFFFFFFFu) && (mb_[2] == 0xFFFFFFFFu) && (mb_[3] == 0xFFFFFFFFu);

    if (allclean) {
        #pragma unroll 2
        for (int r = L_CH - 1; r >= 1; --r) {
            STEP(D0, m0, r); STEP(D1, m1, r); STEP(D2, m2, r); STEP(D3, m3, r);
        }
        if (mb_[0] & 1u) STEP(D0, m0, 0);   // c0==0 has bit0 cleared
        if (mb_[1] & 1u) STEP(D1, m1, 0);
        if (mb_[2] & 1u) STEP(D2, m2, 0);
        if (mb_[3] & 1u) STEP(D3, m3, 0);
    } else {
        for (int r = L_CH - 1; r >= 0; --r) {
            if ((mb_[0] >> r) & 1u) STEP(D0, m0, r);
            if ((mb_[1] >> r) & 1u) STEP(D1, m1, r);
            if ((mb_[2] >> r) & 1u) STEP(D2, m2, r);
            if ((mb_[3] >> r) & 1u) STEP(D3, m3, r);
        }
    }
    #undef STEP

    #define STORE(D, q_) { \
        unsigned* dst = wsf + ((size_t)(b * C_CH + c0 + (q_)) * 64 + lane) * 8; \
        ((uint4*)dst)[0] = make_uint4(pkrtz(D[0], D[1]),   pkrtz(D[2], D[3]), \
                                      pkrtz(D[4], D[5]),   pkrtz(D[6], D[7])); \
        ((uint4*)dst)[1] = make_uint4(pkrtz(D[8], D[9]),   pkrtz(D[10], D[11]), \
                                      pkrtz(D[12], D[13]), pkrtz(D[14], D[15])); \
    }
    STORE(D0, 0) STORE(D1, 1) STORE(D2, 2) STORE(D3, 3)
    #undef STORE

    // ---- last block of this batch runs the combine inline ----
    __threadfence();
    __syncthreads();
    if (threadIdx.x == 0) {
        int* ready = (int*)&wsflt[WS_READY_OFF];
        winner = (atomicAdd(&ready[b], 1) == 1) ? 1 : 0;
    }
    __syncthreads();
    if (!winner || wib != 0) return;
    __threadfence();   // acquire: other block's fragment stores

    int idxA[8], idxB[8];
    #pragma unroll
    for (int j = 0; j < 8; ++j) {
        idxA[j] = PIx(8 * h + j);
        idxB[j] = PIx(16 + 8 * h + j);
    }

    float a0 = startT[n] + em[(size_t)b * S_N * T_N + n];
    float m = a0;
    #pragma unroll
    for (int d = 16; d > 0; d >>= 1) m = fmaxf(m, __shfl_xor(m, d, 32));
    float A = __expf(a0 - m);
    float Lacc = m;
    float ntot = (lane < 32) ? wsflt[WS_NAPP_OFF + b * C_CH + lane] : 0.0f;

    const uint4* fb = (const uint4*)(wsf + (size_t)b * C_CH * 512);
    uint4 q0 = fb[lane * 2];
    uint4 q1 = fb[lane * 2 + 1];

    for (int c = 0; c < C_CH; ++c) {
        uint4 n0 = q0, n1 = q1;
        if (c + 1 < C_CH) {                      // prefetch next chunk's fragment
            n0 = fb[(c + 1) * 128 + lane * 2];
            n1 = fb[(c + 1) * 128 + lane * 2 + 1];
        }

        float p0 = 0.f, p1 = 0.f, p2 = 0.f, p3 = 0.f;
        p0 = fmaf(__shfl(A, idxA[0], 32), hlo(q0.x), p0);
        p1 = fmaf(__shfl(A, idxA[1], 32), hhi(q0.x), p1);
        p2 = fmaf(__shfl(A, idxA[2], 32), hlo(q0.y), p2);
        p3 = fmaf(__shfl(A, idxA[3], 32), hhi(q0.y), p3);
        p0 = fmaf(__shfl(A, idxA[4], 32), hlo(q0.z), p0);
        p1 = fmaf(__shfl(A, idxA[5], 32), hhi(q0.z), p1);
        p2 = fmaf(__shfl(A, idxA[6], 32), hlo(q0.w), p2);
        p3 = fmaf(__shfl(A, idxA[7], 32), hhi(q0.w), p3);
        p0 = fmaf(__shfl(A, idxB[0], 32), hlo(q1.x), p0);
        p1 = fmaf(__shfl(A, idxB[1], 32), hhi(q1.x), p1);
        p2 = fmaf(__shfl(A, idxB[2], 32), hlo(q1.y), p2);
        p3 = fmaf(__shfl(A, idxB[3], 32), hhi(q1.y), p3);
        p0 = fmaf(__shfl(A, idxB[4], 32), hlo(q1.z), p0);
        p1 = fmaf(__shfl(A, idxB[5], 32), hhi(q1.z), p1);
        p2 = fmaf(__shfl(A, idxB[6], 32), hlo(q1.w), p2);
        p3 = fmaf(__shfl(A, idxB[7], 32), hhi(q1.w), p3);
        float part = (p0 + p1) + (p2 + p3);
        part += __shfl_xor(part, 32);           // fold half-wave partials

        float mm = part;
        #pragma unroll
        for (int d = 16; d > 0; d >>= 1) mm = fmaxf(mm, __shfl_xor(mm, d, 32));
        A = part / mm;
        Lacc += __logf(mm);
        q0 = n0; q1 = n1;
    }

    float v = A * __expf(endT[n]);
    #pragma unroll
    for (int d = 16; d > 0; d >>= 1) {
        v    += __shfl_xor(v, d, 32);
        ntot += __shfl_xor(ntot, d, 32);
    }
    if (lane == 0) {
        const int len = (int)(wsflt[WS_MSUM_OFF + b] + 0.5f);
        const int lt  = tags[b * S_N + len - 1];
        const float res = Lacc + __logf(v) + ntot * SCALE_LOG
                          - endT[lt] - wsflt[WS_SCORE_OFF + b];
        atomicAdd(out, res);
    }
}

extern "C" void kernel_launch(void* const* d_in, const int* in_sizes, int n_in,
                              void* d_out, int out_size, void* d_ws, size_t ws_size,
                              hipStream_t stream) {
    const float* em     = (const float*)d_in[0];
    const int*   tags   = (const int*)  d_in[1];
    const float* mask   = (const float*)d_in[2];
    const float* trans  = (const float*)d_in[3];
    const float* startT = (const float*)d_in[4];
    const float* endT   = (const float*)d_in[5];
    float* out = (float*)d_out;

    unsigned* wsf   = (unsigned*)d_ws;
    float*    wsflt = (float*)d_ws;

    hipMemsetAsync(out, 0, sizeof(float), stream);
    // zero msum + score + ready (6 KiB)
    hipMemsetAsync((char*)d_ws + WS_MSUM_OFF * 4, 0, 6144, stream);

    // 512 batches x 2 half-batches; 4 waves x 4 chains; 32 KiB LDS, 4 blocks/CU
    hipLaunchKernelGGL(crf_chunk, dim3(1024), dim3(256), 0, stream,
                       em, tags, mask, trans, startT, endT, wsf, wsflt, out);
}

// Round 9
// 161.491 us; speedup vs baseline: 1.9291x; 1.9291x over previous
//
#include <hip/hip_runtime.h>
#include <hip/hip_fp16.h>

// CRF NLL on MI355X — round 9: f16 chain, phase-split scheduling, 3 dispatches.
//
// partition_b = log( a0 . (prod_t M_t) . exp(end) ),  M_t = ET . diag(ee_t).
// 32 chunks x 32 matrices per batch; each wave runs 4 interleaved chains
// (2 blocks/batch, 4 waves/block, 4 blocks/CU). f16 step: S = pk_mul(
// pkrtz(D), s) -> mfma_f32_32x32x16_f16, PI-aligned (C/D order == next B
// order, zero cross-lane). Per iteration ALL 8 ds_read_b128 issue first,
// then per-chain pack->MFMA: chain q+1's packs fill chain q's MFMA shadow.
// NO cross-block dataflow (r8's per-block __threadfence was a 1024x L2
// writeback disaster). msum/score are per-wave slot writes -> no ws memset.
// Scale 2^-6.5 per matrix (exact: added back as napp*6.5*ln2).
//
// ws (dwords): [0, FRAG) fragments (512 per (b,c));
//   FRAG+0..4095 msum slots [b*8+w]; +4096..8191 score slots;
//   +8192.. napp[b*32+c].

typedef __attribute__((ext_vector_type(8)))  _Float16 half8;
typedef __attribute__((ext_vector_type(2)))  _Float16 half2v;
typedef __attribute__((ext_vector_type(16))) float    f32x16;
typedef __attribute__((ext_vector_type(4)))  unsigned uint4v;

#define S_N 1024
#define T_N 32
#define B_N 512
#define L_CH 32
#define C_CH 32
#define SCALE_MUL 0.011048543456039806f   // 2^-6.5 folded into ee
#define SCALE_LOG 4.505456673639645f      // 6.5*ln2 per applied matrix

#define WS_FRAG_DW ((size_t)B_N * C_CH * 512)          // 32 MiB
#define WS_MSUM_OFF (WS_FRAG_DW)
#define WS_SCORE_OFF (WS_FRAG_DW + 4096)
#define WS_NAPP_OFF (WS_FRAG_DW + 8192)

__device__ __forceinline__ unsigned pkrtz(float lo, float hi) {
    return __builtin_bit_cast(unsigned, __builtin_amdgcn_cvt_pkrtz(lo, hi));
}
__device__ __forceinline__ unsigned pmul(unsigned a, unsigned b) {
    const __half2 r = __builtin_bit_cast(__half2, a) * __builtin_bit_cast(__half2, b);
    return __builtin_bit_cast(unsigned, r);
}
__device__ __forceinline__ half8 mkh8(const unsigned* a) {
    uint4v u = {a[0], a[1], a[2], a[3]};
    return __builtin_bit_cast(half8, u);
}
__device__ __forceinline__ float hlo(unsigned u) {
    return (float)__builtin_bit_cast(half2v, u).x;
}
__device__ __forceinline__ float hhi(unsigned u) {
    return (float)__builtin_bit_cast(half2v, u).y;
}
// PI: involution swapping rows 4-7<->8-11 and 20-23<->24-27
__device__ __forceinline__ int PIx(int x) { return (x & ~12) | ((x & 4) << 1) | ((x & 8) >> 1); }

__global__ __launch_bounds__(256, 4) void crf_chunk(
    const float* __restrict__ em, const int* __restrict__ tags,
    const float* __restrict__ mask, const float* __restrict__ trans,
    const float* __restrict__ startT, unsigned* __restrict__ wsf,
    float* __restrict__ wsflt)
{
    __shared__ unsigned elds[16][512];     // 32 KiB: 16 chunks x 2 KiB
    const int wib  = threadIdx.x >> 6;
    const int lane = threadIdx.x & 63;
    const int n    = lane & 31;
    const int h    = lane >> 5;
    const int b    = blockIdx.x >> 1;
    const int half = blockIdx.x & 1;
    const int c0   = half * 16 + wib * 4;  // this wave's first chunk

    // ---- stage packed f16 scales for 4 chunks (D-reg-pair order) ----
    #pragma unroll
    for (int q = 0; q < 4; ++q) {
        const float* eq = em + ((size_t)b * S_N + (c0 + q) * L_CH) * T_N;
        unsigned* mq = elds[wib * 4 + q];
        #pragma unroll
        for (int i = 0; i < 8; ++i) {
            const int flat = i * 64 + lane;
            const int r = flat >> 4, m = flat & 15;
            const int base = ((m & 4) << 2) + ((m & 2) << 2) + ((m & 1) << 1) + ((m >> 3) << 2);
            const float2 v = *(const float2*)(eq + r * 32 + base);
            mq[r * 16 + m] = pkrtz(__expf(v.x) * SCALE_MUL, __expf(v.y) * SCALE_MUL);
        }
    }

    // ---- mask ballots (4 chunks) + path-score partial (slot writes) ----
    unsigned mb_[4];
    {
        float vacc = 0.f, macc = 0.f;
        #pragma unroll
        for (int q2 = 0; q2 < 2; ++q2) {
            const int s  = c0 * L_CH + q2 * 64 + lane;
            const float mv = mask[b * S_N + s];
            const unsigned long long mb = __ballot(mv != 0.0f);
            mb_[2 * q2]     = (unsigned)mb;
            mb_[2 * q2 + 1] = (unsigned)(mb >> 32);
            const int tc = tags[b * S_N + s];
            int tp = __shfl_up(tc, 1, 64);
            float val;
            if (lane == 0) {
                if (s == 0) {
                    val = startT[tc] + em[(size_t)b * S_N * T_N + tc];
                } else {
                    tp = tags[b * S_N + s - 1];
                    val = mv * (em[((size_t)b * S_N + s) * T_N + tc] + trans[tp * 32 + tc]);
                }
            } else {
                val = mv * (em[((size_t)b * S_N + s) * T_N + tc] + trans[tp * 32 + tc]);
            }
            vacc += val; macc += mv;
        }
        if (c0 == 0) mb_[0] &= ~1u;        // t=0 has no transition matrix
        #pragma unroll
        for (int d = 32; d > 0; d >>= 1) {
            vacc += __shfl_xor(vacc, d, 64);
            macc += __shfl_xor(macc, d, 64);
        }
        if (lane == 0) {
            const int slot = b * 8 + half * 4 + wib;
            wsflt[WS_SCORE_OFF + slot] = vacc;
            wsflt[WS_MSUM_OFF + slot]  = macc;
            #pragma unroll
            for (int q = 0; q < 4; ++q)
                wsflt[WS_NAPP_OFF + b * C_CH + c0 + q] = (float)__popc(mb_[q]);
        }
    }

    // ---- loop-invariant A fragments: f16(exp(trans)), PI-permuted cols ----
    unsigned A1[4], A2[4];
    #pragma unroll
    for (int j = 0; j < 4; ++j) {
        const int k1 = PIx(8 * h + 2 * j);
        const int k2 = PIx(16 + 8 * h + 2 * j);
        A1[j] = pkrtz(__expf(trans[n * 32 + k1]), __expf(trans[n * 32 + k1 + 1]));
        A2[j] = pkrtz(__expf(trans[n * 32 + k2]), __expf(trans[n * 32 + k2 + 1]));
    }
    const half8 A1v = mkh8(A1), A2v = mkh8(A2);
    const f32x16 Zacc = {};

    // ---- 4 chain states: identity in C layout ----
    f32x16 D0, D1, D2, D3;
    #pragma unroll
    for (int i = 0; i < 16; ++i) {
        const int row = (i & 3) + 8 * (i >> 2) + 4 * h;
        const float v = (row == n) ? 1.0f : 0.0f;
        D0[i] = v; D1[i] = v; D2[i] = v; D3[i] = v;
    }

    const unsigned* m0 = elds[wib * 4];
    const unsigned* m1 = elds[wib * 4 + 1];
    const unsigned* m2 = elds[wib * 4 + 2];
    const unsigned* m3 = elds[wib * 4 + 3];

    // pack + 2 MFMAs for one chain (loads already issued)
    #define PACKMM(D, su, sv) { \
        unsigned S[8]; \
        S[0] = pmul(pkrtz(D[0],  D[1]),  su.x); \
        S[1] = pmul(pkrtz(D[2],  D[3]),  su.y); \
        S[2] = pmul(pkrtz(D[4],  D[5]),  su.z); \
        S[3] = pmul(pkrtz(D[6],  D[7]),  su.w); \
        S[4] = pmul(pkrtz(D[8],  D[9]),  sv.x); \
        S[5] = pmul(pkrtz(D[10], D[11]), sv.y); \
        S[6] = pmul(pkrtz(D[12], D[13]), sv.z); \
        S[7] = pmul(pkrtz(D[14], D[15]), sv.w); \
        f32x16 t_ = __builtin_amdgcn_mfma_f32_32x32x16_f16(A1v, mkh8(&S[0]), Zacc, 0, 0, 0); \
        D = __builtin_amdgcn_mfma_f32_32x32x16_f16(A2v, mkh8(&S[4]), t_, 0, 0, 0); \
    }
    // fallback masked step (load inside; rare path)
    #define STEP1(D, mq, r_) { \
        const uint4 su = *(const uint4*)((mq) + (r_) * 16 + h * 8); \
        const uint4 sv = *(const uint4*)((mq) + (r_) * 16 + h * 8 + 4); \
        PACKMM(D, su, sv) \
    }

    const bool allclean =
        ((mb_[0] | (c0 == 0 ? 1u : 0u)) == 0xFFFFFFFFu) &&
        (mb_[1] == 0xFFFFFFFFu) && (mb_[2] == 0xFFFFFFFFu) && (mb_[3] == 0xFFFFFFFFu);

    if (allclean) {
        #pragma unroll 2
        for (int r = L_CH - 1; r >= 1; --r) {
            // phase 1: all 8 loads issue back-to-back
            const uint4 su0 = *(const uint4*)(m0 + r * 16 + h * 8);
            const uint4 sv0 = *(const uint4*)(m0 + r * 16 + h * 8 + 4);
            const uint4 su1 = *(const uint4*)(m1 + r * 16 + h * 8);
            const uint4 sv1 = *(const uint4*)(m1 + r * 16 + h * 8 + 4);
            const uint4 su2 = *(const uint4*)(m2 + r * 16 + h * 8);
            const uint4 sv2 = *(const uint4*)(m2 + r * 16 + h * 8 + 4);
            const uint4 su3 = *(const uint4*)(m3 + r * 16 + h * 8);
            const uint4 sv3 = *(const uint4*)(m3 + r * 16 + h * 8 + 4);
            // phase 2: chain q's MFMA shadow filled by chain q+1's packs
            PACKMM(D0, su0, sv0)
            PACKMM(D1, su1, sv1)
            PACKMM(D2, su2, sv2)
            PACKMM(D3, su3, sv3)
        }
        if (mb_[0] & 1u) STEP1(D0, m0, 0);   // c0==0 has bit0 cleared
        if (mb_[1] & 1u) STEP1(D1, m1, 0);
        if (mb_[2] & 1u) STEP1(D2, m2, 0);
        if (mb_[3] & 1u) STEP1(D3, m3, 0);
    } else {
        for (int r = L_CH - 1; r >= 0; --r) {
            if ((mb_[0] >> r) & 1u) STEP1(D0, m0, r);
            if ((mb_[1] >> r) & 1u) STEP1(D1, m1, r);
            if ((mb_[2] >> r) & 1u) STEP1(D2, m2, r);
            if ((mb_[3] >> r) & 1u) STEP1(D3, m3, r);
        }
    }
    #undef PACKMM
    #undef STEP1

    #define STORE(D, q_) { \
        unsigned* dst = wsf + ((size_t)(b * C_CH + c0 + (q_)) * 64 + lane) * 8; \
        ((uint4*)dst)[0] = make_uint4(pkrtz(D[0], D[1]),   pkrtz(D[2], D[3]), \
                                      pkrtz(D[4], D[5]),   pkrtz(D[6], D[7])); \
        ((uint4*)dst)[1] = make_uint4(pkrtz(D[8], D[9]),   pkrtz(D[10], D[11]), \
                                      pkrtz(D[12], D[13]), pkrtz(D[14], D[15])); \
    }
    STORE(D0, 0) STORE(D1, 1) STORE(D2, 2) STORE(D3, 3)
    #undef STORE
}

// one wave per batch: 32-step alpha row-vector chain over the chunk products
__global__ __launch_bounds__(256) void crf_combine(
    const float* __restrict__ em, const int* __restrict__ tags,
    const float* __restrict__ startT, const float* __restrict__ endT,
    const unsigned* __restrict__ wsf, const float* __restrict__ wsflt,
    float* __restrict__ out)
{
    const int lane = threadIdx.x & 63;
    const int n = lane & 31, h = lane >> 5;
    const int b = blockIdx.x * 4 + (threadIdx.x >> 6);

    int idxA[8], idxB[8];
    #pragma unroll
    for (int j = 0; j < 8; ++j) {
        idxA[j] = PIx(8 * h + j);
        idxB[j] = PIx(16 + 8 * h + j);
    }

    float a0 = startT[n] + em[(size_t)b * S_N * T_N + n];
    float m = a0;
    #pragma unroll
    for (int d = 16; d > 0; d >>= 1) m = fmaxf(m, __shfl_xor(m, d, 32));
    float A = __expf(a0 - m);
    float Lacc = m;
    float ntot = (lane < 32) ? wsflt[WS_NAPP_OFF + b * C_CH + lane] : 0.0f;
    float msum = (lane < 8) ? wsflt[WS_MSUM_OFF + b * 8 + lane] : 0.0f;
    float scor = (lane < 8) ? wsflt[WS_SCORE_OFF + b * 8 + lane] : 0.0f;

    const uint4* fb = (const uint4*)(wsf + (size_t)b * C_CH * 512);
    uint4 q0 = fb[lane * 2];
    uint4 q1 = fb[lane * 2 + 1];

    for (int c = 0; c < C_CH; ++c) {
        uint4 n0 = q0, n1 = q1;
        if (c + 1 < C_CH) {                      // prefetch next chunk's fragment
            n0 = fb[(c + 1) * 128 + lane * 2];
            n1 = fb[(c + 1) * 128 + lane * 2 + 1];
        }

        float p0 = 0.f, p1 = 0.f, p2 = 0.f, p3 = 0.f;
        p0 = fmaf(__shfl(A, idxA[0], 32), hlo(q0.x), p0);
        p1 = fmaf(__shfl(A, idxA[1], 32), hhi(q0.x), p1);
        p2 = fmaf(__shfl(A, idxA[2], 32), hlo(q0.y), p2);
        p3 = fmaf(__shfl(A, idxA[3], 32), hhi(q0.y), p3);
        p0 = fmaf(__shfl(A, idxA[4], 32), hlo(q0.z), p0);
        p1 = fmaf(__shfl(A, idxA[5], 32), hhi(q0.z), p1);
        p2 = fmaf(__shfl(A, idxA[6], 32), hlo(q0.w), p2);
        p3 = fmaf(__shfl(A, idxA[7], 32), hhi(q0.w), p3);
        p0 = fmaf(__shfl(A, idxB[0], 32), hlo(q1.x), p0);
        p1 = fmaf(__shfl(A, idxB[1], 32), hhi(q1.x), p1);
        p2 = fmaf(__shfl(A, idxB[2], 32), hlo(q1.y), p2);
        p3 = fmaf(__shfl(A, idxB[3], 32), hhi(q1.y), p3);
        p0 = fmaf(__shfl(A, idxB[4], 32), hlo(q1.z), p0);
        p1 = fmaf(__shfl(A, idxB[5], 32), hhi(q1.z), p1);
        p2 = fmaf(__shfl(A, idxB[6], 32), hlo(q1.w), p2);
        p3 = fmaf(__shfl(A, idxB[7], 32), hhi(q1.w), p3);
        float part = (p0 + p1) + (p2 + p3);
        part += __shfl_xor(part, 32);           // fold half-wave partials

        float mm = part;
        #pragma unroll
        for (int d = 16; d > 0; d >>= 1) mm = fmaxf(mm, __shfl_xor(mm, d, 32));
        A = part / mm;
        Lacc += __logf(mm);
        q0 = n0; q1 = n1;
    }

    float v = A * __expf(endT[n]);
    #pragma unroll
    for (int d = 16; d > 0; d >>= 1) {
        v    += __shfl_xor(v, d, 32);
        ntot += __shfl_xor(ntot, d, 32);
        msum += __shfl_xor(msum, d, 32);
        scor += __shfl_xor(scor, d, 32);
    }
    if (lane == 0) {
        const int len = (int)(msum + 0.5f);
        const int lt  = tags[b * S_N + len - 1];
        const float res = Lacc + __logf(v) + ntot * SCALE_LOG - endT[lt] - scor;
        atomicAdd(out, res);
    }
}

extern "C" void kernel_launch(void* const* d_in, const int* in_sizes, int n_in,
                              void* d_out, int out_size, void* d_ws, size_t ws_size,
                              hipStream_t stream) {
    const float* em     = (const float*)d_in[0];
    const int*   tags   = (const int*)  d_in[1];
    const float* mask   = (const float*)d_in[2];
    const float* trans  = (const float*)d_in[3];
    const float* startT = (const float*)d_in[4];
    const float* endT   = (const float*)d_in[5];
    float* out = (float*)d_out;

    unsigned* wsf   = (unsigned*)d_ws;
    float*    wsflt = (float*)d_ws;

    hipMemsetAsync(out, 0, sizeof(float), stream);

    // 512 batches x 2 half-batches; 4 waves x 4 chains; 32 KiB LDS, 4 blocks/CU
    hipLaunchKernelGGL(crf_chunk, dim3(1024), dim3(256), 0, stream,
                       em, tags, mask, trans, startT, wsf, wsflt);
    hipLaunchKernelGGL(crf_combine, dim3(128), dim3(256), 0, stream,
                       em, tags, startT, endT, wsf, wsflt, out);
}